// Round 18
// baseline (544.474 us; speedup 1.0000x reference)
//
#include <hip/hip_runtime.h>
#include <hip/hip_cooperative_groups.h>
#include <math.h>

namespace cg = cooperative_groups;

#define NUM_CLASSES 81
#define TOP_K       200
#define NBINS       2048   // fallback histogram (exact threshold-finder at any NBINS)
#define CAND_MAX    512
#define NSORT       512
#define CONF_THRESH 0.05f
#define NMS_THRESH  0.45f
#define CSTRIDE     16     // one 64B line per counter (R2: false-sharing fix)
#define CBLOCKS     2048   // exact machine capacity: 8 blk/CU x 256 CU
#define SCAP        512    // per-block staging
#define FT          256    // finalize: thread t owns sort slots t, t+256
#define T0F (4076.0f / 4096.0f)
// Exact threshold test for fl32(inter/denom) > 0.45f (R14): M has 25 mantissa
// bits, denom 24 -> M*(double)denom exact (49<53), comparison bit-exact.
#define IOU_M 0x1.CCCCCDp-2

// ===========================================================================
// Shared-memory union layout (u32 indices into s_mem[3840], 15360 B):
//   collect : key u64 [0..1024) | bcnt [1024..1672) | bbase [1672..2320)
//             meta [2320..2832) | total [2832]
//   finalize: sk u64 [0..1024) | sup[200][8] [1024..2624) | bbox f4 [2624..3424)
//             bar [3424..3624) | bsc [3624..3824) | keep [3824..3832)
//             rm [3832..3840)  | (fallback hist[2048] aliases [1024..3072))
// ===========================================================================

__device__ __forceinline__ void collect_body(
    unsigned* s_mem,
    const float4* __restrict__ conf4,
    unsigned long long* __restrict__ cand,   // [nbc][CAND_MAX]
    int* __restrict__ counts,                // [nbc * CSTRIDE]
    unsigned AC, unsigned N4, int nbc, int ashift)
{
    unsigned long long* s_key = (unsigned long long*)s_mem;    // [512]
    int* s_bcnt  = (int*)(s_mem + 1024);                       // [648]
    int* s_bbase = (int*)(s_mem + 1672);                       // [648]
    unsigned* s_meta = s_mem + 2320;                           // [512]
    int* s_total = (int*)(s_mem + 2832);

    const int tid = threadIdx.x;

    // zero-fold: first instruction; all CBLOCKS co-resident, reserve atomics
    // fire only after ~20us of streaming -> ordering safe (R17).
    if (tid == 0 && blockIdx.x < (unsigned)nbc)
        atomicExch(&counts[blockIdx.x * CSTRIDE], 0);

    for (int i = tid; i < nbc; i += 256) s_bcnt[i] = 0;
    if (tid == 0) *s_total = 0;
    __syncthreads();

    auto process = [&](float4 v4, unsigned t) {
        float vs[4] = {v4.x, v4.y, v4.z, v4.w};
#pragma unroll
        for (int j = 0; j < 4; ++j) {
            float v = vs[j];
            if (v > T0F) {                       // ~0.5% of elements
                unsigned e = 4u * t + (unsigned)j;
                unsigned a, b, c;
                if (ashift) {                    // wave-uniform branch
                    unsigned q = e / NUM_CLASSES;        // magic mul
                    c = e - q * NUM_CLASSES;
                    a = q & ((1u << ashift) - 1u);
                    b = q >> ashift;
                } else {
                    b = e / AC;
                    unsigned rem = e - b * AC;
                    a = rem / NUM_CLASSES;
                    c = rem - a * NUM_CLASSES;
                }
                unsigned bc  = b * NUM_CLASSES + c;
                unsigned long long key =
                    ((unsigned long long)__float_as_uint(v) << 32) |
                    (unsigned)(~a);
                int sp = atomicAdd(s_total, 1);
                if (sp < SCAP) {
                    int p = atomicAdd(&s_bcnt[bc], 1);
                    s_key[sp]  = key;
                    s_meta[sp] = bc | ((unsigned)p << 16);
                } else {
                    int gp = atomicAdd(&counts[bc * CSTRIDE], 1);
                    if (gp < CAND_MAX)
                        cand[(size_t)bc * CAND_MAX + gp] = key;
                }
            }
        }
    };

    // 4-deep ILP (8-deep was null, R14 — collect is HBM-BW-bound)
    unsigned per = (N4 + gridDim.x - 1) / gridDim.x;
    unsigned lo  = blockIdx.x * per;
    unsigned hi  = lo + per; if (hi > N4) hi = N4;
    unsigned last = N4 - 1;

    for (unsigned t = lo + tid; t < hi; t += 1024) {
        unsigned t1 = t + 256, t2 = t + 512, t3 = t + 768;
        float4 v0 = conf4[t];
        float4 v1 = conf4[t1 < hi ? t1 : last];
        float4 v2 = conf4[t2 < hi ? t2 : last];
        float4 v3 = conf4[t3 < hi ? t3 : last];
        process(v0, t);
        if (t1 < hi) process(v1, t1);
        if (t2 < hi) process(v2, t2);
        if (t3 < hi) process(v3, t3);
    }
    __syncthreads();

    for (int i = tid; i < nbc; i += 256) {
        int cloc = s_bcnt[i];
        if (cloc > 0) s_bbase[i] = atomicAdd(&counts[i * CSTRIDE], cloc);
    }
    __syncthreads();

    int total = *s_total < SCAP ? *s_total : SCAP;
    for (int s = tid; s < total; s += 256) {
        unsigned meta = s_meta[s];
        unsigned bc   = meta & 0xFFFFu;
        unsigned p    = meta >> 16;
        long long g   = (long long)s_bbase[bc] + (long long)p;
        if (g < CAND_MAX)
            cand[(size_t)bc * CAND_MAX + g] = s_key[s];
    }
}

__device__ __forceinline__ void finalize_body(
    unsigned* s_mem,
    const float* __restrict__ loc,
    const float* __restrict__ conf,
    const float* __restrict__ anchors,
    const unsigned long long* __restrict__ cand,
    const int* __restrict__ counts,
    float* __restrict__ out,
    int A, int use_ws, int nbc, int bc)
{
    unsigned long long* sk = (unsigned long long*)s_mem;    // [512]
    unsigned (*sup)[8] = (unsigned(*)[8])(s_mem + 1024);    // [200][8]
    int* hist = (int*)(s_mem + 1024);                       // [2048] fallback
    float4* bbox = (float4*)(s_mem + 2624);                 // [200]
    float* bar = (float*)(s_mem + 3424);                    // [200]
    float* bsc = (float*)(s_mem + 3624);                    // [200]
    unsigned* s_keep = s_mem + 3824;                        // [8]
    unsigned* s_rm   = s_mem + 3832;                        // [8]
    int* s_cnt  = (int*)(s_mem + 3824);                     // fallback-only alias
    int* s_tbin = (int*)(s_mem + 3825);

    const int tid = threadIdx.x;
    const int b   = bc / NUM_CLASSES;
    const int c   = bc % NUM_CLASSES;

    unsigned long long v0 = 0ULL, v1 = 0ULL;
    int cnt = -1;
    if (use_ws) {
        cnt = counts[bc * CSTRIDE];
        if (cnt >= TOP_K && cnt <= CAND_MAX) {
            if (tid < cnt)       v0 = cand[(size_t)bc * CAND_MAX + tid];
            if (tid + FT < cnt)  v1 = cand[(size_t)bc * CAND_MAX + tid + FT];
        } else {
            cnt = -1;
        }
    }

    if (cnt < 0) {
        // ---- Fallback: strided scan (+ exact histogram select) ----
        const float* cp = conf + (size_t)b * A * NUM_CLASSES + c;
        if (tid == 0) *s_cnt = 0;
        __syncthreads();
        for (int a = tid; a < A; a += FT) {
            float val = cp[(size_t)a * NUM_CLASSES];
            if (val > T0F) {
                int pos = atomicAdd(s_cnt, 1);
                if (pos < CAND_MAX)
                    sk[pos] = ((unsigned long long)__float_as_uint(val) << 32) |
                              (unsigned)(~(unsigned)a);
            }
        }
        __syncthreads();
        cnt = *s_cnt;
        if (cnt < TOP_K || cnt > CAND_MAX) {
            for (int i = tid; i < NBINS; i += FT) hist[i] = 0;
            __syncthreads();
            for (int a = tid; a < A; a += FT) {
                float val = cp[(size_t)a * NUM_CLASSES];
                if (val > CONF_THRESH) {
                    int bin = (int)(val * (float)NBINS);
                    bin = bin < 0 ? 0 : (bin > NBINS - 1 ? NBINS - 1 : bin);
                    atomicAdd(&hist[bin], 1);
                }
            }
            __syncthreads();
            if (tid == 0) {
                int acc = 0, t = NBINS - 1;
                for (; t > 0; --t) { acc += hist[t]; if (acc >= TOP_K) break; }
                *s_tbin = t;
                *s_cnt  = 0;
            }
            __syncthreads();
            int tb = *s_tbin;
            for (int a = tid; a < A; a += FT) {
                float val = cp[(size_t)a * NUM_CLASSES];
                if (val > CONF_THRESH) {
                    int bin = (int)(val * (float)NBINS);
                    bin = bin < 0 ? 0 : (bin > NBINS - 1 ? NBINS - 1 : bin);
                    if (bin >= tb) {
                        int pos = atomicAdd(s_cnt, 1);
                        if (pos < CAND_MAX)
                            sk[pos] = ((unsigned long long)__float_as_uint(val) << 32) |
                                      (unsigned)(~(unsigned)a);
                    }
                }
            }
            __syncthreads();
            cnt = *s_cnt < CAND_MAX ? *s_cnt : CAND_MAX;
        }
        for (int i = cnt + tid; i < NSORT; i += FT) sk[i] = 0ULL;
        __syncthreads();
        v0 = sk[tid];
        v1 = sk[tid + FT];
        __syncthreads();
    }

    // ---- Hybrid bitonic sort (descending), 2 slots/thread (R17 network) ----
    for (int k = 2; k <= NSORT; k <<= 1) {
        for (int j = k >> 1; j > 0; j >>= 1) {
            const int s0 = tid, s1 = tid + FT;
            bool d0 = ((s0 & k) == 0) ^ ((s0 & j) != 0);
            bool d1 = ((s1 & k) == 0) ^ ((s1 & j) != 0);
            if (j == FT) {
                unsigned long long mx = v0 > v1 ? v0 : v1;
                unsigned long long mn = v0 > v1 ? v1 : v0;
                v0 = d0 ? mx : mn;
                v1 = d1 ? mx : mn;
            } else if (j >= 64) {
                sk[s0] = v0; sk[s1] = v1;
                __syncthreads();
                unsigned long long u0 = sk[s0 ^ j];
                unsigned long long u1 = sk[s1 ^ j];
                __syncthreads();
                v0 = d0 ? (v0 > u0 ? v0 : u0) : (v0 < u0 ? v0 : u0);
                v1 = d1 ? (v1 > u1 ? v1 : u1) : (v1 < u1 ? v1 : u1);
            } else {
                unsigned h0 = __shfl_xor((unsigned)(v0 >> 32), j, 64);
                unsigned l0 = __shfl_xor((unsigned)(v0 & 0xFFFFFFFFu), j, 64);
                unsigned h1 = __shfl_xor((unsigned)(v1 >> 32), j, 64);
                unsigned l1 = __shfl_xor((unsigned)(v1 & 0xFFFFFFFFu), j, 64);
                unsigned long long u0 = ((unsigned long long)h0 << 32) | l0;
                unsigned long long u1 = ((unsigned long long)h1 << 32) | l1;
                v0 = d0 ? (v0 > u0 ? v0 : u0) : (v0 < u0 ? v0 : u0);
                v1 = d1 ? (v1 > u1 ? v1 : u1) : (v1 < u1 ? v1 : u1);
            }
        }
    }

    // ---- Decode top-200 + zero sup/keep/rowmask ----
    for (int i = tid; i < 1600; i += FT) s_mem[1024 + i] = 0;   // sup
    if (tid < 8)  s_keep[tid] = 0;
    if (tid >= 8 && tid < 16) s_rm[tid - 8] = 0;
    if (tid < TOP_K) {
        unsigned long long key = v0;
        float sc = 0.f, x0 = 0.f, y0 = 0.f, x1 = 0.f, y1 = 0.f;
        if (key != 0ULL) {
            sc = __uint_as_float((unsigned)(key >> 32));
            unsigned idx = ~(unsigned)(key & 0xFFFFFFFFu);
            const float* lp = loc + ((size_t)b * A + idx) * 4;
            const float* ap = anchors + (size_t)idx * 4;
            float l0 = lp[0], l1 = lp[1], l2 = lp[2], l3 = lp[3];
            float acx = ap[0], acy = ap[1], aw = ap[2], ah = ap[3];
            float cx = __fadd_rn(acx, __fmul_rn(__fmul_rn(l0, 0.1f), aw));
            float cy = __fadd_rn(acy, __fmul_rn(__fmul_rn(l1, 0.1f), ah));
            float ew = (float)exp((double)__fmul_rn(l2, 0.2f));
            float eh = (float)exp((double)__fmul_rn(l3, 0.2f));
            float w  = __fmul_rn(aw, ew);
            float h  = __fmul_rn(ah, eh);
            float hw = __fmul_rn(w, 0.5f), hh = __fmul_rn(h, 0.5f);
            x0 = __fsub_rn(cx, hw); y0 = __fsub_rn(cy, hh);
            x1 = __fadd_rn(cx, hw); y1 = __fadd_rn(cy, hh);
        }
        bbox[tid] = make_float4(x0, y0, x1, y1);
        bar[tid] = __fmul_rn(__fsub_rn(x1, x0), __fsub_rn(y1, y0));
        bsc[tid] = sc;
    }
    __syncthreads();

    // ---- Suppression bitmask + rowmask (packed b128, exact f64 IoU test) ----
    if (tid < TOP_K && bsc[tid] > CONF_THRESH)
        atomicOr(&s_keep[tid >> 5], 1u << (tid & 31));
    {
        const int wave = tid >> 6, lane = tid & 63;       // 4 waves
        for (int i = wave; i < TOP_K - 1; i += FT / 64) {
            float4 bi = bbox[i];
            float iar = bar[i];
            for (int j = i + 1 + lane; j < TOP_K; j += 64) {
                float4 bj = bbox[j];
                float iw = fmaxf(__fsub_rn(fminf(bi.z, bj.z),
                                           fmaxf(bi.x, bj.x)), 0.f);
                float ih = fmaxf(__fsub_rn(fminf(bi.w, bj.w),
                                           fmaxf(bi.y, bj.y)), 0.f);
                float inter = __fmul_rn(iw, ih);
                float denom = __fadd_rn(
                    __fsub_rn(__fadd_rn(iar, bar[j]), inter), 1e-9f);
                if ((double)inter > IOU_M * (double)denom) {
                    atomicOr(&sup[i][j >> 5], 1u << (j & 31));
                    atomicOr(&s_rm[i >> 5], 1u << (i & 31));
                }
            }
        }
    }
    __syncthreads();

    // ---- Keep propagation, wave 0 (R13-proven rowmask walk) ----
    if (tid < 64) {
        unsigned keepw = (tid < 7) ? s_keep[tid] : 0u;
        unsigned act0 = s_rm[0], act1 = s_rm[1], act2 = s_rm[2], act3 = s_rm[3];
        unsigned act4 = s_rm[4], act5 = s_rm[5], act6 = s_rm[6];
#define PROP_BITS(ACT, BASE)                                           \
        while (ACT) {                                                  \
            int i = (BASE) + (__ffs(ACT) - 1);                         \
            unsigned kw = __shfl(keepw, i >> 5, 64);                   \
            if ((kw >> (i & 31)) & 1u) {                               \
                if (tid < 7) keepw &= ~sup[i][tid];                    \
            }                                                          \
            ACT &= ACT - 1;                                            \
        }
        PROP_BITS(act0, 0)
        PROP_BITS(act1, 32)
        PROP_BITS(act2, 64)
        PROP_BITS(act3, 96)
        PROP_BITS(act4, 128)
        PROP_BITS(act5, 160)
        PROP_BITS(act6, 192)
#undef PROP_BITS
        if (tid < 7) s_keep[tid] = keepw;
    }
    __syncthreads();

    // ---- Write outputs (score plane offset uses nbc, NOT gridDim.x) ----
    if (tid < TOP_K) {
        int kp = (s_keep[tid >> 5] >> (tid & 31)) & 1u;
        float4 bo = bbox[tid];
        size_t lb = ((size_t)bc * TOP_K + tid) * 4;
        out[lb + 0] = kp ? bo.x : 0.f;
        out[lb + 1] = kp ? bo.y : 0.f;
        out[lb + 2] = kp ? bo.z : 0.f;
        out[lb + 3] = kp ? bo.w : 0.f;
        out[(size_t)nbc * TOP_K * 4 + (size_t)bc * TOP_K + tid] =
            kp ? bsc[tid] : 0.f;
    }
}

// ---------------------------------------------------------------------------
// R18 fused cooperative kernel: collect -> device fence -> grid sync ->
// finalize (blocks 0..nbc-1). Removes one kernel boundary + launch ramp.
// __launch_bounds__(256,8): 8 waves/SIMD -> <=64 VGPR -> 8 blocks/CU -> the
// CBLOCKS=2048 grid is exactly co-resident (cooperative requirement).
// ---------------------------------------------------------------------------
__global__ __launch_bounds__(256, 8) void fused_kernel(
    const float4* __restrict__ conf4,
    unsigned long long* __restrict__ cand,
    int* __restrict__ counts,
    const float* __restrict__ loc,
    const float* __restrict__ anchors,
    float* __restrict__ out,
    unsigned AC, unsigned N4, int nbc, int ashift, int A)
{
    __shared__ unsigned s_mem[3840];   // 15360 B union
    collect_body(s_mem, conf4, cand, counts, AC, N4, nbc, ashift);
    __threadfence();                   // release: flush cross-XCD visibility
    cg::this_grid().sync();
    if ((int)blockIdx.x < nbc) {
        __threadfence();               // acquire side
        __syncthreads();
        finalize_body(s_mem, loc, (const float*)conf4, anchors, cand, counts,
                      out, A, 1, nbc, (int)blockIdx.x);
    }
}

// ---- Standalone fallback kernels (two-kernel R17 path) ----
__global__ __launch_bounds__(256) void collect_kernel(
    const float4* __restrict__ conf4, unsigned long long* __restrict__ cand,
    int* __restrict__ counts, unsigned AC, unsigned N4, int nbc, int ashift)
{
    __shared__ unsigned s_mem[2840];
    collect_body(s_mem, conf4, cand, counts, AC, N4, nbc, ashift);
}

__global__ __launch_bounds__(FT) void finalize_kernel(
    const float* __restrict__ loc, const float* __restrict__ conf,
    const float* __restrict__ anchors,
    const unsigned long long* __restrict__ cand, const int* __restrict__ counts,
    float* __restrict__ out, int A, int use_ws, int nbc)
{
    __shared__ unsigned s_mem[3840];
    finalize_body(s_mem, loc, conf, anchors, cand, counts, out, A, use_ws,
                  nbc, (int)blockIdx.x);
}

extern "C" void kernel_launch(void* const* d_in, const int* in_sizes, int n_in,
                              void* d_out, int out_size, void* d_ws, size_t ws_size,
                              hipStream_t stream) {
    const float* loc     = (const float*)d_in[0];
    const float* conf    = (const float*)d_in[1];
    const float* anchors = (const float*)d_in[2];
    float* out = (float*)d_out;

    int A = in_sizes[2] / 4;                 // anchors: [A,4]
    int B = in_sizes[0] / (A * 4);           // preds_loc: [B,A,4]
    int BC = B * NUM_CLASSES;

    int ashift = 0;
    if ((A & (A - 1)) == 0) { while ((1 << ashift) != A) ++ashift; }

    size_t counts_bytes = (size_t)BC * CSTRIDE * sizeof(int);
    counts_bytes = (counts_bytes + 4095) & ~(size_t)4095;
    size_t cand_bytes = (size_t)BC * CAND_MAX * sizeof(unsigned long long);
    int use_ws = (ws_size >= counts_bytes + cand_bytes &&
                  BC <= NUM_CLASSES * 8 && BC <= CBLOCKS) ? 1 : 0;

    int* counts = (int*)d_ws;
    unsigned long long* cand = (unsigned long long*)((char*)d_ws + counts_bytes);

    unsigned AC = (unsigned)A * NUM_CLASSES;
    unsigned N4 = (unsigned)B * AC / 4u;

    if (use_ws) {
        // ---- Try the fused cooperative path ----
        const float4* conf4 = (const float4*)conf;
        void* args[] = {
            (void*)&conf4, (void*)&cand, (void*)&counts,
            (void*)&loc, (void*)&anchors, (void*)&out,
            (void*)&AC, (void*)&N4, (void*)&BC, (void*)&ashift, (void*)&A
        };
        hipError_t e = hipLaunchCooperativeKernel(
            reinterpret_cast<void*>(&fused_kernel),
            dim3(CBLOCKS), dim3(256), args, 0, stream);
        if (e == hipSuccess) return;
        (void)hipGetLastError();   // clear error; deterministic fallback below
        collect_kernel<<<CBLOCKS, 256, 0, stream>>>(
            conf4, cand, counts, AC, N4, BC, ashift);
    }

    finalize_kernel<<<BC, FT, 0, stream>>>(
        loc, conf, anchors, cand, counts, out, A, use_ws, BC);
}

// Round 19
// 73.592 us; speedup vs baseline: 7.3985x; 7.3985x over previous
//
#include <hip/hip_runtime.h>
#include <hip/hip_bf16.h>
#include <math.h>

#define NUM_CLASSES 81
#define TOP_K       200
#define NBINS       4096
#define CAND_MAX    512
#define NSORT       512
#define CONF_THRESH 0.05f
#define NMS_THRESH  0.45f
#define CSTRIDE     16     // one 64B line per counter (R2: false-sharing fix)
#define CBLOCKS     2048   // collect grid: 8 blocks/CU -> 32 waves/CU TLP
#define SCAP        512    // per-block staging (mean ~202, +22 sigma)
#define FTHREADS    512    // finalize block: thread i owns sort slot i
// Collection threshold: 4076/4096 (exact in f32). E[count] = 65536*20/4096 = 320
// per column, sigma ~= 17.9; [200, 512] window is -6.7 / +10.7 sigma.
#define T0F (4076.0f / 4096.0f)
// Exact threshold test for fl32(inter/denom) > 0.45f:
//   quotient > M, M = midpoint(0.45f, nextafterf) = 0x1.CCCCCDp-2. M has 25
//   mantissa bits, denom 24 -> M*(double)denom is EXACT (49 < 53 bits), so
//   the comparison reproduces the f32-divide+compare bit-exactly.
#define IOU_M 0x1.CCCCCDp-2

// ---------------------------------------------------------------------------
// Kernel 0: zero the padded counters (replaces hipMemsetAsync, ~96us runtime fill).
// ---------------------------------------------------------------------------
__global__ __launch_bounds__(256) void zero_counts_kernel(
    int* __restrict__ counts, int nbc)
{
    int t = blockIdx.x * blockDim.x + threadIdx.x;
    if (t < nbc) counts[t * CSTRIDE] = 0;
}

// ---------------------------------------------------------------------------
// Kernel 1: coalesced pass over conf; 8 outstanding float4 loads/iter.
// R8/R14: collect is HBM-BW-bound at ~27us (the 170MB streaming floor).
// R18 lesson: do NOT add occupancy-forcing launch bounds here — the register
// clamp (VGPR 28) destroyed the load pipeline (611us).
// conf flat index e = (b*A + a)*81 + c -> q = e/81 = b*A + a.
// ---------------------------------------------------------------------------
__global__ __launch_bounds__(256) void collect_kernel(
    const float4* __restrict__ conf4,
    unsigned long long* __restrict__ cand,   // [nbc][CAND_MAX]
    int* __restrict__ counts,                // [nbc * CSTRIDE]
    unsigned AC,                             // A * 81
    unsigned N4,                             // total floats / 4
    int nbc,                                 // B * 81
    int ashift)                              // log2(A) if A pow2, else 0
{
    __shared__ int s_bcnt[NUM_CLASSES * 8];          // per-bucket local count
    __shared__ int s_bbase[NUM_CLASSES * 8];         // reserved global base
    __shared__ unsigned long long s_key[SCAP];
    __shared__ unsigned s_meta[SCAP];                // bc | (local_pos << 16)
    __shared__ int s_total;

    const int tid = threadIdx.x;

    for (int i = tid; i < nbc; i += 256) s_bcnt[i] = 0;
    if (tid == 0) s_total = 0;
    __syncthreads();

    auto process = [&](float4 v4, unsigned t) {
        float vs[4] = {v4.x, v4.y, v4.z, v4.w};
#pragma unroll
        for (int j = 0; j < 4; ++j) {
            float v = vs[j];
            if (v > T0F) {                       // ~0.5% of elements
                unsigned e = 4u * t + (unsigned)j;
                unsigned a, b, c;
                if (ashift) {                    // wave-uniform branch
                    unsigned q = e / NUM_CLASSES;        // magic mul (constexpr)
                    c = e - q * NUM_CLASSES;
                    a = q & ((1u << ashift) - 1u);
                    b = q >> ashift;
                } else {                         // generic (runtime div) path
                    b = e / AC;
                    unsigned rem = e - b * AC;
                    a = rem / NUM_CLASSES;
                    c = rem - a * NUM_CLASSES;
                }
                unsigned bc  = b * NUM_CLASSES + c;
                unsigned long long key =
                    ((unsigned long long)__float_as_uint(v) << 32) |
                    (unsigned)(~a);
                int sp = atomicAdd(&s_total, 1);
                if (sp < SCAP) {
                    int p = atomicAdd(&s_bcnt[bc], 1);
                    s_key[sp]  = key;
                    s_meta[sp] = bc | ((unsigned)p << 16);
                } else {
                    // staging overflow (never on this data): direct global path
                    int gp = atomicAdd(&counts[bc * CSTRIDE], 1);
                    if (gp < CAND_MAX)
                        cand[(size_t)bc * CAND_MAX + gp] = key;
                }
            }
        }
    };

    // ---- Stream a contiguous chunk: 8 independent loads per iteration ----
    unsigned per = (N4 + gridDim.x - 1) / gridDim.x;
    unsigned lo  = blockIdx.x * per;
    unsigned hi  = lo + per; if (hi > N4) hi = N4;
    unsigned last = N4 - 1;

    for (unsigned t = lo + tid; t < hi; t += 2048) {
        unsigned ti[8];
        float4 vv[8];
#pragma unroll
        for (int s = 0; s < 8; ++s) {
            ti[s] = t + 256u * s;
            vv[s] = conf4[ti[s] < hi ? ti[s] : last];  // clamped loads safe;
        }                                              // OOB guarded below
        process(vv[0], t);
#pragma unroll
        for (int s = 1; s < 8; ++s)
            if (ti[s] < hi) process(vv[s], ti[s]);
    }
    __syncthreads();

    // ---- Reserve per-bucket ranges: one global atomic per non-empty bucket ----
    for (int i = tid; i < nbc; i += 256) {
        int cloc = s_bcnt[i];
        if (cloc > 0) s_bbase[i] = atomicAdd(&counts[i * CSTRIDE], cloc);
    }
    __syncthreads();

    // ---- Scatter staged candidates with plain stores ----
    int total = s_total < SCAP ? s_total : SCAP;
    for (int s = tid; s < total; s += 256) {
        unsigned meta = s_meta[s];
        unsigned bc   = meta & 0xFFFFu;
        unsigned p    = meta >> 16;
        long long g   = (long long)s_bbase[bc] + (long long)p;
        if (g < CAND_MAX)
            cand[(size_t)bc * CAND_MAX + g] = s_key[s];
    }
}

// ---------------------------------------------------------------------------
// Kernel 2: per-(b,c) finalize (R16 form — session best, post-timing-proven).
// Hybrid shuffle-bitonic sort, packed float4 boxes, exact f64-midpoint IoU
// test, rowmask-skipped keep propagation (R13).
// ---------------------------------------------------------------------------
__global__ __launch_bounds__(FTHREADS) void finalize_kernel(
    const float* __restrict__ loc,      // [B, A, 4]
    const float* __restrict__ conf,     // [B, A*81] (fallback path only)
    const float* __restrict__ anchors,  // [A, 4]
    const unsigned long long* __restrict__ cand,
    const int* __restrict__ counts,
    float* __restrict__ out,
    int A, int use_ws)
{
    __shared__ unsigned long long sk[NSORT];       // 4 KB (big-j phases + fallback)
    __shared__ unsigned s_scratch[NBINS];          // 16 KB, multi-purpose
    __shared__ int s_cnt;
    __shared__ int s_tbin;

    int* hist = (int*)s_scratch;                           // fallback only
    unsigned (*sup)[8] = (unsigned(*)[8])s_scratch;        // [200][8] = 1600 u32
    float4* bbox = (float4*)(s_scratch + 1600);            // [200] float4
    float* bar = (float*)(s_scratch + 2400);               // [200]
    float* bsc = (float*)(s_scratch + 2600);               // [200]
    unsigned* s_keep = s_scratch + 2800;                   // [8]
    unsigned* s_rm   = s_scratch + 2808;                   // [8] rowmask

    const int tid = threadIdx.x;
    const int bc  = blockIdx.x;
    const int b   = bc / NUM_CLASSES;
    const int c   = bc % NUM_CLASSES;

    // ---- Get this thread's sort element into register v ----
    unsigned long long v = 0ULL;
    int cnt = -1;
    if (use_ws) {
        cnt = counts[bc * CSTRIDE];
        if (cnt >= TOP_K && cnt <= CAND_MAX) {
            if (tid < cnt) v = cand[(size_t)bc * CAND_MAX + tid];
        } else {
            cnt = -1;  // trigger fallback
        }
    }

    if (cnt < 0) {
        // ---- Fallback: strided scan (+ exact histogram select if needed) ----
        const float* cp = conf + (size_t)b * A * NUM_CLASSES + c;
        if (tid == 0) s_cnt = 0;
        __syncthreads();
        for (int a = tid; a < A; a += FTHREADS) {
            float val = cp[(size_t)a * NUM_CLASSES];
            if (val > T0F) {
                int pos = atomicAdd(&s_cnt, 1);
                if (pos < CAND_MAX)
                    sk[pos] = ((unsigned long long)__float_as_uint(val) << 32) |
                              (unsigned)(~(unsigned)a);
            }
        }
        __syncthreads();
        cnt = s_cnt;
        if (cnt < TOP_K || cnt > CAND_MAX) {
            for (int i = tid; i < NBINS; i += FTHREADS) hist[i] = 0;
            __syncthreads();
            for (int a = tid; a < A; a += FTHREADS) {
                float val = cp[(size_t)a * NUM_CLASSES];
                if (val > CONF_THRESH) {
                    int bin = (int)(val * (float)NBINS);
                    bin = bin < 0 ? 0 : (bin > NBINS - 1 ? NBINS - 1 : bin);
                    atomicAdd(&hist[bin], 1);
                }
            }
            __syncthreads();
            if (tid == 0) {
                int acc = 0, t = NBINS - 1;
                for (; t > 0; --t) { acc += hist[t]; if (acc >= TOP_K) break; }
                s_tbin = t;
                s_cnt  = 0;
            }
            __syncthreads();
            int tb = s_tbin;
            for (int a = tid; a < A; a += FTHREADS) {
                float val = cp[(size_t)a * NUM_CLASSES];
                if (val > CONF_THRESH) {
                    int bin = (int)(val * (float)NBINS);
                    bin = bin < 0 ? 0 : (bin > NBINS - 1 ? NBINS - 1 : bin);
                    if (bin >= tb) {
                        int pos = atomicAdd(&s_cnt, 1);
                        if (pos < CAND_MAX)
                            sk[pos] = ((unsigned long long)__float_as_uint(val) << 32) |
                                      (unsigned)(~(unsigned)a);
                    }
                }
            }
            __syncthreads();
            cnt = s_cnt < CAND_MAX ? s_cnt : CAND_MAX;
        }
        // pad and move to register
        for (int i = cnt + tid; i < NSORT; i += FTHREADS) sk[i] = 0ULL;
        __syncthreads();
        v = sk[tid];
    }

    // ---- Hybrid bitonic sort, descending: register CE via shuffle (j<64),
    //      LDS CE only for j>=64 ----
    for (int k = 2; k <= NSORT; k <<= 1) {
        for (int j = k >> 1; j > 0; j >>= 1) {
            bool keepMax = ((tid & k) == 0) ^ ((tid & j) != 0);
            unsigned long long u;
            if (j >= 64) {
                sk[tid] = v;
                __syncthreads();
                u = sk[tid ^ j];
                __syncthreads();
            } else {
                unsigned hi32 = __shfl_xor((unsigned)(v >> 32), j, 64);
                unsigned lo32 = __shfl_xor((unsigned)(v & 0xFFFFFFFFu), j, 64);
                u = ((unsigned long long)hi32 << 32) | lo32;
            }
            v = keepMax ? (v > u ? v : u) : (v < u ? v : u);
        }
    }

    // ---- Decode top-200 (f32 ops in reference order; no FMA contraction),
    //      and zero sup/keep/rowmask in parallel ----
    for (int i = tid; i < 1600; i += FTHREADS) s_scratch[i] = 0;   // sup
    if (tid < 8)  s_keep[tid] = 0;
    if (tid >= 8 && tid < 16) s_rm[tid - 8] = 0;
    if (tid < TOP_K) {
        unsigned long long key = v;
        float sc = 0.f, x0 = 0.f, y0 = 0.f, x1 = 0.f, y1 = 0.f;
        if (key != 0ULL) {
            sc = __uint_as_float((unsigned)(key >> 32));
            unsigned idx = ~(unsigned)(key & 0xFFFFFFFFu);
            const float* lp = loc + ((size_t)b * A + idx) * 4;
            const float* ap = anchors + (size_t)idx * 4;
            float l0 = lp[0], l1 = lp[1], l2 = lp[2], l3 = lp[3];
            float acx = ap[0], acy = ap[1], aw = ap[2], ah = ap[3];
            float cx = __fadd_rn(acx, __fmul_rn(__fmul_rn(l0, 0.1f), aw));
            float cy = __fadd_rn(acy, __fmul_rn(__fmul_rn(l1, 0.1f), ah));
            float ew = (float)exp((double)__fmul_rn(l2, 0.2f));
            float eh = (float)exp((double)__fmul_rn(l3, 0.2f));
            float w  = __fmul_rn(aw, ew);
            float h  = __fmul_rn(ah, eh);
            float hw = __fmul_rn(w, 0.5f), hh = __fmul_rn(h, 0.5f);
            x0 = __fsub_rn(cx, hw); y0 = __fsub_rn(cy, hh);
            x1 = __fadd_rn(cx, hw); y1 = __fadd_rn(cy, hh);
        }
        bbox[tid] = make_float4(x0, y0, x1, y1);
        bar[tid] = __fmul_rn(__fsub_rn(x1, x0), __fsub_rn(y1, y0));
        bsc[tid] = sc;
    }
    __syncthreads();

    // ---- Build suppression bitmask + rowmask; packed b128 box read,
    //      branchless clamp, exact f64 midpoint IoU test ----
    if (tid < TOP_K && bsc[tid] > CONF_THRESH)
        atomicOr(&s_keep[tid >> 5], 1u << (tid & 31));
    {
        const int wave = tid >> 6, lane = tid & 63;       // 8 waves
        for (int i = wave; i < TOP_K - 1; i += FTHREADS / 64) {
            float4 bi = bbox[i];
            float iar = bar[i];
            for (int j = i + 1 + lane; j < TOP_K; j += 64) {
                float4 bj = bbox[j];                       // ds_read_b128
                float iw = fmaxf(__fsub_rn(fminf(bi.z, bj.z),
                                           fmaxf(bi.x, bj.x)), 0.f);
                float ih = fmaxf(__fsub_rn(fminf(bi.w, bj.w),
                                           fmaxf(bi.y, bj.y)), 0.f);
                float inter = __fmul_rn(iw, ih);
                float denom = __fadd_rn(
                    __fsub_rn(__fadd_rn(iar, bar[j]), inter), 1e-9f);
                if ((double)inter > IOU_M * (double)denom) {
                    atomicOr(&sup[i][j >> 5], 1u << (j & 31));
                    atomicOr(&s_rm[i >> 5], 1u << (i & 31));
                }
            }
        }
    }
    __syncthreads();

    // ---- Keep propagation, wave 0: shfl keep test + conditional sup AND,
    //      iterating only rows present in rowmask (R13-proven). ----
    if (tid < 64) {
        unsigned keepw = (tid < 7) ? s_keep[tid] : 0u;
        unsigned act0 = s_rm[0], act1 = s_rm[1], act2 = s_rm[2], act3 = s_rm[3];
        unsigned act4 = s_rm[4], act5 = s_rm[5], act6 = s_rm[6];
#define PROP_BITS(ACT, BASE)                                           \
        while (ACT) {                                                  \
            int i = (BASE) + (__ffs(ACT) - 1);                         \
            unsigned kw = __shfl(keepw, i >> 5, 64);                   \
            if ((kw >> (i & 31)) & 1u) {                               \
                if (tid < 7) keepw &= ~sup[i][tid];                    \
            }                                                          \
            ACT &= ACT - 1;                                            \
        }
        PROP_BITS(act0, 0)
        PROP_BITS(act1, 32)
        PROP_BITS(act2, 64)
        PROP_BITS(act3, 96)
        PROP_BITS(act4, 128)
        PROP_BITS(act5, 160)
        PROP_BITS(act6, 192)
#undef PROP_BITS
        if (tid < 7) s_keep[tid] = keepw;
    }
    __syncthreads();

    // ---- Write outputs ----
    if (tid < TOP_K) {
        int kp = (s_keep[tid >> 5] >> (tid & 31)) & 1u;
        float4 bo = bbox[tid];
        size_t lb = ((size_t)bc * TOP_K + tid) * 4;
        out[lb + 0] = kp ? bo.x : 0.f;
        out[lb + 1] = kp ? bo.y : 0.f;
        out[lb + 2] = kp ? bo.z : 0.f;
        out[lb + 3] = kp ? bo.w : 0.f;
        out[(size_t)gridDim.x * TOP_K * 4 + (size_t)bc * TOP_K + tid] =
            kp ? bsc[tid] : 0.f;
    }
}

extern "C" void kernel_launch(void* const* d_in, const int* in_sizes, int n_in,
                              void* d_out, int out_size, void* d_ws, size_t ws_size,
                              hipStream_t stream) {
    const float* loc     = (const float*)d_in[0];
    const float* conf    = (const float*)d_in[1];
    const float* anchors = (const float*)d_in[2];
    float* out = (float*)d_out;

    int A = in_sizes[2] / 4;                 // anchors: [A,4]
    int B = in_sizes[0] / (A * 4);           // preds_loc: [B,A,4]
    int BC = B * NUM_CLASSES;

    int ashift = 0;
    if ((A & (A - 1)) == 0) { while ((1 << ashift) != A) ++ashift; }

    size_t counts_bytes = (size_t)BC * CSTRIDE * sizeof(int);
    counts_bytes = (counts_bytes + 4095) & ~(size_t)4095;   // align cand region
    size_t cand_bytes = (size_t)BC * CAND_MAX * sizeof(unsigned long long);
    int use_ws = (ws_size >= counts_bytes + cand_bytes && BC <= NUM_CLASSES * 8) ? 1 : 0;

    int* counts = (int*)d_ws;
    unsigned long long* cand = (unsigned long long*)((char*)d_ws + counts_bytes);

    if (use_ws) {
        unsigned AC = (unsigned)A * NUM_CLASSES;
        unsigned N4 = (unsigned)B * AC / 4u;
        zero_counts_kernel<<<(BC + 255) / 256, 256, 0, stream>>>(counts, BC);
        collect_kernel<<<CBLOCKS, 256, 0, stream>>>(
            (const float4*)conf, cand, counts, AC, N4, BC, ashift);
    }

    finalize_kernel<<<BC, FTHREADS, 0, stream>>>(
        loc, conf, anchors, cand, counts, out, A, use_ws);
}